// Round 4
// baseline (429.903 us; speedup 1.0000x reference)
//
#include <hip/hip_runtime.h>
#include <hip/hip_bf16.h>
#include <float.h>
#include <stdint.h>

// Forbid FMA contraction: reference (numpy fp32) rounds every mul/add
// separately; a fused (a1+a2)-iw*ih could flip an iou>0.5 decision.
#pragma clang fp contract(off)

#define NEGV   (-1e9f)
#define THRV   (0.05f)
#define MAXDET 100
#define NBKT   32
#define BKT_INV 0.03125f   // 1/32 px bucket width (exact pow2 scale)

__device__ __forceinline__ void amax2(float& v, int& i, float ov, int oi) {
  if (ov > v || (ov == v && oi < i)) { v = ov; i = oi; }
}

// monotone float->u32 map (total order preserved)
__device__ __forceinline__ unsigned mapf(float v) {
  const unsigned u = __float_as_uint(v);
  return (u & 0x80000000u) ? ~u : (u | 0x80000000u);
}
__device__ __forceinline__ float unmapf(unsigned m) {
  const unsigned u = (m & 0x80000000u) ? (m & 0x7FFFFFFFu) : ~m;
  return __uint_as_float(u);
}

__device__ __forceinline__ int bucketOf(float x) {
  int v = (int)(x * BKT_INV);           // exact scale; trunc==floor for x>=0
  return v < 0 ? 0 : (v > NBKT - 1 ? NBKT - 1 : v);
}

// ---- DPP wave64 reductions (VALU pipe) ------------------------------------
#define DPP_MAXF(v, CTRL) do {                                               \
    int _t = __builtin_amdgcn_update_dpp(__float_as_int(v), __float_as_int(v),\
                                         CTRL, 0xF, 0xF, false);             \
    (v) = fmaxf((v), __int_as_float(_t)); } while (0)
#define DPP_MINU(v, CTRL) do {                                               \
    unsigned _t = (unsigned)__builtin_amdgcn_update_dpp((int)(v), (int)(v),  \
                                         CTRL, 0xF, 0xF, false);             \
    (v) = ((v) < _t ? (v) : _t); } while (0)

__device__ __forceinline__ float wave_fmax_b(float v) {
  DPP_MAXF(v, 0x111); DPP_MAXF(v, 0x112); DPP_MAXF(v, 0x114); DPP_MAXF(v, 0x118);
  DPP_MAXF(v, 0x142); DPP_MAXF(v, 0x143);
  return __int_as_float(__builtin_amdgcn_readlane(__float_as_int(v), 63));
}
__device__ __forceinline__ unsigned wave_umin_b(unsigned v) {
  DPP_MINU(v, 0x111); DPP_MINU(v, 0x112); DPP_MINU(v, 0x114); DPP_MINU(v, 0x118);
  DPP_MINU(v, 0x142); DPP_MINU(v, 0x143);
  return (unsigned)__builtin_amdgcn_readlane((int)v, 63);
}

// ---------------------------------------------------------------------------
// Kernel 0: per-image bucketing by x1 (unstable counting sort, 32 buckets)
// + wmax = max box x-width. Order within bucket is irrelevant: tie-breaks
// downstream use the original index carried in perm[].
// ---------------------------------------------------------------------------
template<int BT>
__global__ __launch_bounds__(BT, 1) void bucket_kernel(
    const float* __restrict__ boxes, int* __restrict__ perm,
    float4* __restrict__ sbox, int* __restrict__ jbucket,
    float* __restrict__ wmaxArr, int N)
{
  const int b = blockIdx.x;
  const int tid = threadIdx.x, lane = tid & 63, wid = tid >> 6;
  constexpr int NW = BT / 64;
  const float4* bb = (const float4*)(boxes + (size_t)b * N * 4);

  __shared__ int hist[NW][NBKT];
  __shared__ int cur[NBKT];
  __shared__ float wm[NW];
  for (int i = tid; i < NW * NBKT; i += BT) hist[i / NBKT][i % NBKT] = 0;
  __syncthreads();

  float mw = 0.f;
  for (int i = tid; i < N; i += BT) {
    const float4 v = bb[i];
    atomicAdd(&hist[wid][bucketOf(v.x)], 1);
    mw = fmaxf(mw, v.z - v.x);
  }
  mw = wave_fmax_b(mw);
  if (lane == 0) wm[wid] = mw;
  __syncthreads();

  if (wid == 0) {
    // lanes 0..31: column sums then exclusive scan across 32 lanes
    int colsum = 0;
    if (lane < NBKT)
      for (int w = 0; w < NW; ++w) colsum += hist[w][lane];
    int inc = colsum;
#pragma unroll
    for (int off = 1; off < 32; off <<= 1) {
      const int u = __shfl_up(inc, off, 64);
      if (lane >= off) inc += u;
    }
    if (lane < NBKT) cur[lane] = inc - colsum;
    if (lane == 0) {
      float w0 = wm[0];
      for (int w = 1; w < NW; ++w) w0 = fmaxf(w0, wm[w]);
      wmaxArr[b] = w0;
    }
  }
  __syncthreads();

  for (int i = tid; i < N; i += BT) {
    const float4 v = bb[i];
    const int bkt = bucketOf(v.x);
    const int pos = atomicAdd(&cur[bkt], 1);
    perm[(size_t)b * N + pos] = i;
    sbox[(size_t)b * N + pos] = v;
    jbucket[(size_t)b * N + pos] = bkt;
  }
}

// ---------------------------------------------------------------------------
// Kernel 1: per-(image,class) stable compaction (over bucketed order) of
// scores > 0.05, plus per-class bucket-start table for pruning.
// ---------------------------------------------------------------------------
template<int BT>
__global__ __launch_bounds__(BT, 1) void compact_kernel(
    const float* __restrict__ cls, const int* __restrict__ perm,
    const int* __restrict__ jbucket, int* __restrict__ cnt,
    float* __restrict__ cscore, int* __restrict__ cj,
    int* __restrict__ cbstart, int N, int C)
{
  const int bc = blockIdx.x;
  const int b = bc / C, c = bc % C;
  const int tid = threadIdx.x, lane = tid & 63, wid = tid >> 6;
  const int chunk = (N + BT - 1) / BT;
  const int j0 = tid * chunk;
  const int j1 = min(N, j0 + chunk);
  const float* cp = cls + (size_t)b * N * C + c;
  const int* pm = perm + (size_t)b * N;
  const int* jb = jbucket + (size_t)b * N;

  __shared__ int cbs[NBKT + 1];
  __shared__ int wtot[BT / 64];
  __shared__ int totSh;
  if (tid < NBKT + 1) cbs[tid] = 0x7FFFFFFF;

  int cntt = 0;
  for (int j = j0; j < j1; ++j)
    cntt += (cp[(size_t)pm[j] * C] > THRV) ? 1 : 0;

  int inc = cntt;
#pragma unroll
  for (int off = 1; off < 64; off <<= 1) {
    const int u = __shfl_up(inc, off, 64);
    if (lane >= off) inc += u;
  }
  if (lane == 63) wtot[wid] = inc;
  __syncthreads();                      // also fences cbs init
  int base = 0;
  for (int w = 0; w < wid; ++w) base += wtot[w];
  int pos = base + inc - cntt;

  for (int j = j0; j < j1; ++j) {
    const float s = cp[(size_t)pm[j] * C];
    if (s > THRV) {
      cscore[(size_t)bc * N + pos] = s;
      cj[(size_t)bc * N + pos] = j;
      atomicMin(&cbs[jb[j]], pos);
      ++pos;
    }
  }
  if (tid == BT - 1) { totSh = base + inc; cnt[bc] = base + inc; }
  __syncthreads();
  if (tid == 0) {
    int run = totSh;
    cbs[NBKT] = run;
    for (int bkt = NBKT - 1; bkt >= 0; --bkt) {
      run = min(run, cbs[bkt]);
      cbs[bkt] = run;
    }
    for (int bkt = 0; bkt <= NBKT; ++bkt)
      cbstart[(size_t)bc * (NBKT + 1) + bkt] = cbs[bkt];
  }
}

// ---------------------------------------------------------------------------
// Kernel 2: register-resident greedy NMS with x-bucket pruning.
// 1 barrier/iter, DPP reductions, tie-break on ORIGINAL index.
// Pruned slots are provably inter==0 => reference also keeps them.
// ---------------------------------------------------------------------------
template<int KM, int BT>
__global__ __launch_bounds__(BT, 1) void nms_kernel(
    const int* __restrict__ cnt, const float* __restrict__ cscore,
    const int* __restrict__ cj, const int* __restrict__ perm,
    const float4* __restrict__ sbox, const int* __restrict__ cbstart,
    const float* __restrict__ wmaxArr,
    float* __restrict__ ksc, float* __restrict__ kbx, int N, int C)
{
#pragma clang fp contract(off)
  const int bc = blockIdx.x;
  const int cn = cnt[bc];
  if (cn > KM * BT) return;            // fallback kernel owns this block
  const int b = bc / C;
  const int tid = threadIdx.x, lane = tid & 63, wid = tid >> 6;
  constexpr int NW = BT / 64;

  float sc[KM], px1[KM], py1[KM], px2[KM], py2[KM], ar[KM];
  int   kd[KM];                         // original index (tie-break key)
  const float wmax = wmaxArr[b];
  const float* cs = cscore + (size_t)bc * N;
  const int*   cjj = cj + (size_t)bc * N;
  const int*   pm = perm + (size_t)b * N;
  const float4* sb = sbox + (size_t)b * N;

  __shared__ int cbs[NBKT + 1];
  __shared__ unsigned long long red[2][NW];
  __shared__ float4 wbox[2][NW];
  if (tid < NBKT + 1) cbs[tid] = cbstart[(size_t)bc * (NBKT + 1) + tid];

  float bv = NEGV; int bk = 0x3FFFFFFF;
#pragma unroll
  for (int k = 0; k < KM; ++k) {
    const int p = tid + k * BT;
    sc[k] = NEGV; px1[k] = 0.f; py1[k] = 0.f; px2[k] = 0.f; py2[k] = 0.f;
    ar[k] = 0.f; kd[k] = 0x3FFFFFFF;
    if (p < cn) {
      const int j = cjj[p];
      const float s = cs[p];
      const float4 v = sb[j];
      sc[k] = s; px1[k] = v.x; py1[k] = v.y; px2[k] = v.z; py2[k] = v.w;
      ar[k] = (v.z - v.x) * (v.w - v.y);
      kd[k] = pm[j];
      const bool gt = (s > bv) || ((s == bv) && (kd[k] < bk));
      if (gt) { bv = s; bk = kd[k]; }
    }
  }

  float* ko  = ksc + (size_t)bc * MAXDET;
  float* kbo = kbx + (size_t)bc * MAXDET * 4;

  for (int m = 0; m < MAXDET; ++m) {
    // --- wave argmax: phase1 max score, phase2 min orig-idx among maxima ---
    const float wmx = wave_fmax_b(bv);
    const unsigned gki =
        wave_umin_b((bv == wmx) ? (unsigned)bk : 0xFFFFFFFFu);
    if (lane == 0)
      red[m & 1][wid] = ((unsigned long long)mapf(wmx) << 32) | ~gki;
    // wave winner's owner lane stages its box (unique orig idx => one lane)
    if (bv == wmx && (unsigned)bk == gki) {
      float ox1 = 0.f, oy1 = 0.f, ox2 = 0.f, oy2 = 0.f;
#pragma unroll
      for (int k = 0; k < KM; ++k)
        if (kd[k] == bk) { ox1 = px1[k]; oy1 = py1[k]; ox2 = px2[k]; oy2 = py2[k]; }
      wbox[m & 1][wid] = make_float4(ox1, oy1, ox2, oy2);
    }
    __syncthreads();                    // the only barrier per iteration
    unsigned long long best = red[m & 1][0];
    int wsel = 0;
#pragma unroll
    for (int w = 1; w < NW; ++w) {
      const unsigned long long o = red[m & 1][w];
      if (o > best) { best = o; wsel = w; }   // (score desc, orig asc)
    }
    const float gv = unmapf((unsigned)(best >> 32));

    if (gv <= THRV) {                   // uniform: nothing valid remains
      for (int mm = m + tid; mm < MAXDET; mm += BT) {
        ko[mm] = NEGV;
        kbo[mm * 4 + 0] = 0.f; kbo[mm * 4 + 1] = 0.f;
        kbo[mm * 4 + 2] = 0.f; kbo[mm * 4 + 3] = 0.f;
      }
      return;
    }
    const float4 q = wbox[m & 1][wsel];
    const float qx1 = q.x, qy1 = q.y, qx2 = q.z, qy2 = q.w;
    const float a1 = (qx2 - qx1) * (qy2 - qy1);
    if (tid == 0) {
      ko[m] = gv;
      kbo[m * 4 + 0] = qx1; kbo[m * 4 + 1] = qy1;
      kbo[m * 4 + 2] = qx2; kbo[m * 4 + 3] = qy2;
    }
    // --- pruned suppress: only p in [lo,hi) can overlap in x ---
    const int blo = bucketOf(qx1 - wmax);
    const int bhi = bucketOf(qx2);
    const int lo = cbs[blo];
    const int hi = cbs[bhi + 1];
    unsigned amb = 0;
#pragma unroll
    for (int k = 0; k < KM; ++k) {
      if (k * BT < cn) {                          // block-uniform
        const int pstart = k * BT + (wid << 6);   // wave-uniform chunk
        if (pstart < hi && pstart + 64 > lo) {
          const float iw = fminf(qx2, px2[k]) - fmaxf(qx1, px1[k]);
          const float ih = fminf(qy2, py2[k]) - fmaxf(qy1, py1[k]);
          const bool ovr = (iw > 0.f) && (ih > 0.f);
          const float inter = ovr ? iw * ih : 0.f;
          const float den = fmaxf((a1 + ar[k]) - inter, 1e-8f);
          const float i2 = inter + inter;
          const bool kill = i2 > den * 1.00001f;
          if (ovr && !kill && (i2 > den * 0.99999f)) amb |= 1u << k;
          if (kill) sc[k] = NEGV;
        }
      }
    }
    if (__builtin_expect(__any(amb != 0), 0)) {
      // exact reference recompute for ambiguous slots
#pragma unroll
      for (int k = 0; k < KM; ++k) {
        if ((amb >> k) & 1u) {
          const float ix1 = fmaxf(qx1, px1[k]);
          const float iy1 = fmaxf(qy1, py1[k]);
          const float ix2 = fminf(qx2, px2[k]);
          const float iy2 = fminf(qy2, py2[k]);
          const float iw = fmaxf(ix2 - ix1, 0.f);
          const float ih = fmaxf(iy2 - iy1, 0.f);
          const float inter = iw * ih;
          const float den = fmaxf((a1 + ar[k]) - inter, 1e-8f);
          if ((inter / den) > 0.5f) sc[k] = NEGV;
        }
      }
    }
    // --- rebuild local argmax (score desc, orig idx asc) ---
    bv = NEGV; bk = 0x3FFFFFFF;
#pragma unroll
    for (int k = 0; k < KM; ++k) {
      if (k * BT < cn) {
        const bool gt = (sc[k] > bv) || ((sc[k] == bv) && (kd[k] < bk));
        if (gt) { bv = sc[k]; bk = kd[k]; }
      }
    }
  }
}

// ---------------------------------------------------------------------------
// Kernel 2b: global-resident fallback for cn > cap (safety net; never runs
// at bench shapes). Packs (origIdx<<14)|p for tie-break + box recovery
// (valid for N < 16384).
// ---------------------------------------------------------------------------
template<int BT>
__global__ __launch_bounds__(BT, 1) void nms_fallback_kernel(
    const int* __restrict__ cnt, float* __restrict__ cscore,
    const int* __restrict__ cj, const int* __restrict__ perm,
    const float4* __restrict__ sbox,
    float* __restrict__ ksc, float* __restrict__ kbx, int N, int C, int cap)
{
#pragma clang fp contract(off)
  const int bc = blockIdx.x;
  const int cn = cnt[bc];
  if (cn <= cap) return;
  const int b = bc / C;
  const int tid = threadIdx.x, lane = tid & 63, wid = tid >> 6;
  constexpr int NW = BT / 64;
  float* cs = cscore + (size_t)bc * N;
  const int* cjj = cj + (size_t)bc * N;
  const int* pm = perm + (size_t)b * N;
  const float4* sb = sbox + (size_t)b * N;
  __shared__ unsigned long long red[NW];
  float* ko  = ksc + (size_t)bc * MAXDET;
  float* kbo = kbx + (size_t)bc * MAXDET * 4;

  for (int m = 0; m < MAXDET; ++m) {
    float bv = NEGV; unsigned bki = 0xFFFFFFFFu;
    for (int p = tid; p < cn; p += BT) {
      const float s = cs[p];
      const unsigned ki = ((unsigned)pm[cjj[p]] << 14) | (unsigned)p;
      if (s > bv || (s == bv && ki < bki)) { bv = s; bki = ki; }
    }
    const float wmx = wave_fmax_b(bv);
    const unsigned gki =
        wave_umin_b((bv == wmx) ? bki : 0xFFFFFFFFu);
    if (lane == 0)
      red[wid] = ((unsigned long long)mapf(wmx) << 32) | ~gki;
    __syncthreads();
    unsigned long long best = red[0];
#pragma unroll
    for (int w = 1; w < NW; ++w) {
      const unsigned long long o = red[w];
      if (o > best) best = o;
    }
    const float gv = unmapf((unsigned)(best >> 32));
    const int gp = (int)(~(unsigned)best & 0x3FFFu);
    __syncthreads();                    // WAR fence for red

    if (gv <= THRV) {
      for (int mm = m + tid; mm < MAXDET; mm += BT) {
        ko[mm] = NEGV;
        kbo[mm * 4 + 0] = 0.f; kbo[mm * 4 + 1] = 0.f;
        kbo[mm * 4 + 2] = 0.f; kbo[mm * 4 + 3] = 0.f;
      }
      return;
    }
    const float4 q = sb[cjj[gp]];
    const float a1 = (q.z - q.x) * (q.w - q.y);
    if (tid == 0) {
      ko[m] = gv;
      kbo[m * 4 + 0] = q.x; kbo[m * 4 + 1] = q.y;
      kbo[m * 4 + 2] = q.z; kbo[m * 4 + 3] = q.w;
    }
    for (int p = tid; p < cn; p += BT) {
      if (cs[p] > NEGV) {
        const float4 v = sb[cjj[p]];
        const float ix1 = fmaxf(q.x, v.x);
        const float iy1 = fmaxf(q.y, v.y);
        const float ix2 = fminf(q.z, v.z);
        const float iy2 = fminf(q.w, v.w);
        const float iw = fmaxf(ix2 - ix1, 0.f);
        const float ih = fmaxf(iy2 - iy1, 0.f);
        const float inter = iw * ih;
        const float a2 = (v.z - v.x) * (v.w - v.y);
        const float den = fmaxf((a1 + a2) - inter, 1e-8f);
        if ((inter / den) > 0.5f) cs[p] = NEGV;
      }
    }
  }
}

// ---------------------------------------------------------------------------
// Kernel 3: per-image top-100 = 80-way merge of per-class descending lists.
// Single wave, DPP reduces, LDS-resident score slab, deferred box gather.
// ---------------------------------------------------------------------------
__global__ __launch_bounds__(64, 1) void topk_kernel(
    const float* __restrict__ ksc, const float* __restrict__ kbx,
    float* __restrict__ out, int B, int C)
{
  const int b = blockIdx.x;
  const int lane = threadIdx.x;
  const int T = C * MAXDET;
  const float* s0 = ksc + (size_t)b * T;
  float* ob = out;                              // [B][100][4]
  float* os = out + (size_t)B * MAXDET * 4;     // [B][100]
  float* ol = os + (size_t)B * MAXDET;          // [B][100] labels as float

  __shared__ float ssc[8192];
  __shared__ int   wfi[MAXDET];
  __shared__ float wsc[MAXDET];
  const bool uselds = (T <= 8192);
  if (uselds)
    for (int i = lane; i < T; i += 64) ssc[i] = s0[i];
  __syncthreads();

  int h0 = 0, h1 = 0;
  const int c0 = lane;
  const int c1 = lane + 64;

  for (int m = 0; m < MAXDET; ++m) {
    float bv = -FLT_MAX; int bf = 0x7FFFFFFF;
    if (c0 < C && h0 < MAXDET) {
      const int f = c0 * MAXDET + h0;
      amax2(bv, bf, uselds ? ssc[f] : s0[f], f);
    }
    if (c1 < C && h1 < MAXDET) {
      const int f = c1 * MAXDET + h1;
      amax2(bv, bf, uselds ? ssc[f] : s0[f], f);
    }
    const float gmax = wave_fmax_b(bv);
    if (gmax <= THRV) {
      for (int mm = m + lane; mm < MAXDET; mm += 64) wfi[mm] = -1;
      break;
    }
    const unsigned gf =
        wave_umin_b((bv == gmax) ? (unsigned)bf : 0xFFFFFFFFu);
    const int wc = (int)gf / MAXDET;
    if (lane == (wc & 63)) { if (wc == c0) ++h0; else ++h1; }
    if (lane == 0) { wfi[m] = (int)gf; wsc[m] = gmax; }
  }
  __syncthreads();

  for (int e = lane; e < MAXDET; e += 64) {
    const int f = wfi[e];
    float* od = ob + ((size_t)b * MAXDET + e) * 4;
    if (f < 0) {
      od[0] = -1.f; od[1] = -1.f; od[2] = -1.f; od[3] = -1.f;
      os[(size_t)b * MAXDET + e] = -1.f;
      ol[(size_t)b * MAXDET + e] = -1.f;
    } else {
      const float* bp = kbx + ((size_t)b * T + f) * 4;
      od[0] = bp[0]; od[1] = bp[1]; od[2] = bp[2]; od[3] = bp[3];
      os[(size_t)b * MAXDET + e] = wsc[e];
      ol[(size_t)b * MAXDET + e] = (float)(f / MAXDET);
    }
  }
}

extern "C" void kernel_launch(void* const* d_in, const int* in_sizes, int n_in,
                              void* d_out, int out_size, void* d_ws, size_t ws_size,
                              hipStream_t stream) {
  const float* boxes = (const float*)d_in[0];  // (B, N, 4) f32
  const float* cls   = (const float*)d_in[1];  // (B, N, C) f32
  const int B = out_size / (MAXDET * 6);       // 4 box + 1 score + 1 label
  const int N = in_sizes[0] / (B * 4);
  const int C = in_sizes[1] / (B * N);

  char* ws = (char*)d_ws;
  float4* sbox = (float4*)ws;  ws += (size_t)B * N * 16;            // sorted boxes
  float* kbx = (float*)ws;     ws += (size_t)B * C * MAXDET * 16;   // kept boxes
  float* ksc = (float*)ws;     ws += (size_t)B * C * MAXDET * 4;    // kept scores
  float* cscore = (float*)ws;  ws += (size_t)B * C * N * 4;         // compacted scores
  int* cj = (int*)ws;          ws += (size_t)B * C * N * 4;         // compacted -> sorted pos
  int* perm = (int*)ws;        ws += (size_t)B * N * 4;             // sorted pos -> orig idx
  int* jbucket = (int*)ws;     ws += (size_t)B * N * 4;             // sorted pos -> bucket
  int* cbstart = (int*)ws;     ws += (size_t)B * C * (NBKT + 1) * 4;// class bucket starts
  int* cnt = (int*)ws;         ws += (size_t)B * C * 4;             // alive counts
  float* wmaxArr = (float*)ws;                                      // per-image max width

  bucket_kernel<1024><<<dim3(B), dim3(1024), 0, stream>>>(
      boxes, perm, sbox, jbucket, wmaxArr, N);
  compact_kernel<512><<<dim3(B * C), dim3(512), 0, stream>>>(
      cls, perm, jbucket, cnt, cscore, cj, cbstart, N, C);
  nms_kernel<12, 512><<<dim3(B * C), dim3(512), 0, stream>>>(
      cnt, cscore, cj, perm, sbox, cbstart, wmaxArr, ksc, kbx, N, C);
  nms_fallback_kernel<1024><<<dim3(B * C), dim3(1024), 0, stream>>>(
      cnt, cscore, cj, perm, sbox, ksc, kbx, N, C, 12 * 512);
  topk_kernel<<<dim3(B), dim3(64), 0, stream>>>(ksc, kbx, (float*)d_out, B, C);
}

// Round 5
// 183.113 us; speedup vs baseline: 2.3478x; 2.3478x over previous
//
#include <hip/hip_runtime.h>
#include <hip/hip_bf16.h>
#include <float.h>
#include <stdint.h>

// Forbid FMA contraction: reference (numpy fp32) rounds every mul/add
// separately; a fused (a1+a2)-iw*ih could flip an iou>0.5 decision.
#pragma clang fp contract(off)

#define NEGV   (-1e9f)
#define THRV   (0.05f)
#define MAXDET 100
#define NB     1152        // score buckets (3 per thread at BT=512 -> 384 thr)
#define BKBASE 31385       // (bits(0.05f) >> 15)

__device__ __forceinline__ void amax2(float& v, int& i, float ov, int oi) {
  if (ov > v || (ov == v && oi < i)) { v = ov; i = oi; }
}

__device__ __forceinline__ int bktOf(unsigned u) {
  int v = (int)(u >> 15) - BKBASE;          // monotone in float for s > 0
  return v < 0 ? 0 : (v > NB - 1 ? NB - 1 : v);
}

// ---- DPP wave64 reductions (VALU pipe) — used by topk ---------------------
#define DPP_MAXF(v, CTRL) do {                                               \
    int _t = __builtin_amdgcn_update_dpp(__float_as_int(v), __float_as_int(v),\
                                         CTRL, 0xF, 0xF, false);             \
    (v) = fmaxf((v), __int_as_float(_t)); } while (0)
#define DPP_MINU(v, CTRL) do {                                               \
    unsigned _t = (unsigned)__builtin_amdgcn_update_dpp((int)(v), (int)(v),  \
                                         CTRL, 0xF, 0xF, false);             \
    (v) = ((v) < _t ? (v) : _t); } while (0)

__device__ __forceinline__ float wave_fmax_b(float v) {
  DPP_MAXF(v, 0x111); DPP_MAXF(v, 0x112); DPP_MAXF(v, 0x114); DPP_MAXF(v, 0x118);
  DPP_MAXF(v, 0x142); DPP_MAXF(v, 0x143);
  return __int_as_float(__builtin_amdgcn_readlane(__float_as_int(v), 63));
}
__device__ __forceinline__ unsigned wave_umin_b(unsigned v) {
  DPP_MINU(v, 0x111); DPP_MINU(v, 0x112); DPP_MINU(v, 0x114); DPP_MINU(v, 0x118);
  DPP_MINU(v, 0x142); DPP_MINU(v, 0x143);
  return (unsigned)__builtin_amdgcn_readlane((int)v, 63);
}

// Bit-exact "(iou > 0.5)" decision. Certain cases via the two-sided window
// (margin 1e-5 >> max rounding error); ambiguous window does the exact
// reference IEEE divide. Roles are symmetric (fp add/mul commutative).
__device__ __forceinline__ bool killpair(
    float qx1, float qy1, float qx2, float qy2, float qa,
    float x1, float y1, float x2, float y2, float a)
{
  const float iw = fminf(qx2, x2) - fmaxf(qx1, x1);
  const float ih = fminf(qy2, y2) - fmaxf(qy1, y1);
  if (iw <= 0.f || ih <= 0.f) return false;
  const float inter = iw * ih;
  const float den = fmaxf((qa + a) - inter, 1e-8f);
  const float i2 = inter + inter;
  if (i2 > den * 1.00001f) return true;
  if (i2 < den * 0.99999f) return false;
  return (inter / den) > 0.5f;
}

// ---------------------------------------------------------------------------
// Kernel 1: per-(image,class) sorted-scan NMS.
//   Phase 0-3: counting-sort alive candidates by (score desc, orig idx asc)
//   Phase 4:   batched scan (64/batch): keep iff no kept box IoU>0.5
//   Phase 5:   emit kept list (== greedy selection order)
// ---------------------------------------------------------------------------
template<int K, int BT>
__global__ __launch_bounds__(BT, 1) void nms_kernel(
    const float* __restrict__ boxes, const float* __restrict__ cls,
    unsigned long long* __restrict__ skey,
    float* __restrict__ ksc, float* __restrict__ kbx, int N, int C)
{
#pragma clang fp contract(off)
  const int bc = blockIdx.x;
  const int b = bc / C, c = bc % C;
  const int tid = threadIdx.x, lane = tid & 63, wid = tid >> 6;

  const float* cp = cls + (size_t)b * N * C + c;
  const float4* bb4 = (const float4*)(boxes + (size_t)b * N * 4);
  unsigned long long* sk = skey + (size_t)bc * N;

  __shared__ int hist[NB];
  __shared__ int wtot[BT / 64];
  __shared__ float4 kboxS[MAXDET];
  __shared__ float  kscoreS[MAXDET];
  __shared__ float  kareaS[MAXDET];
  __shared__ unsigned long long wkill[BT / 64];
  __shared__ unsigned long long killby[64];

  // ---- Phase 0: histogram of alive scores (cache score bits in regs) ----
  for (int i = tid; i < NB; i += BT) hist[i] = 0;
  __syncthreads();

  unsigned umask = 0;
  unsigned uu[K];
#pragma unroll
  for (int k = 0; k < K; ++k) {
    const int i = tid + k * BT;
    uu[k] = 0;
    if (i < N) {
      const float s = cp[(size_t)i * C];
      if (s > THRV) {
        uu[k] = __float_as_uint(s);
        umask |= 1u << k;
        atomicAdd(&hist[bktOf(uu[k])], 1);
      }
    }
  }
  for (int i = tid + K * BT; i < N; i += BT) {   // tail (N > K*BT only)
    const float s = cp[(size_t)i * C];
    if (s > THRV) atomicAdd(&hist[bktOf(__float_as_uint(s))], 1);
  }
  __syncthreads();

  // ---- Phase 1: suffix-sum -> hist[bk] = start pos (descending layout) ----
  int cn;
  {
    int c0 = 0, c1 = 0, c2 = 0;
    if (tid < NB / 3) {
      c0 = hist[NB - 1 - 3 * tid];
      c1 = hist[NB - 2 - 3 * tid];
      c2 = hist[NB - 3 - 3 * tid];
    }
    const int tsum = c0 + c1 + c2;
    int inc = tsum;
#pragma unroll
    for (int off = 1; off < 64; off <<= 1) {
      const int u = __shfl_up(inc, off, 64);
      if (lane >= off) inc += u;
    }
    if (lane == 63) wtot[wid] = inc;
    __syncthreads();
    int wbase = 0, cnAll = 0;
#pragma unroll
    for (int w = 0; w < BT / 64; ++w) {
      const int v = wtot[w];
      if (w < wid) wbase += v;
      cnAll += v;
    }
    const int excl = wbase + inc - tsum;
    if (tid < NB / 3) {
      hist[NB - 1 - 3 * tid] = excl;
      hist[NB - 2 - 3 * tid] = excl + c0;
      hist[NB - 3 - 3 * tid] = excl + c0 + c1;
    }
    cn = cnAll;
    __syncthreads();
  }

  // ---- Phase 2: scatter keys (score_bits<<32 | ~idx) into bucket slots ----
#pragma unroll
  for (int k = 0; k < K; ++k) {
    if ((umask >> k) & 1u) {
      const unsigned u = uu[k];
      const int i = tid + k * BT;
      const int pos = atomicAdd(&hist[bktOf(u)], 1);
      sk[pos] = ((unsigned long long)u << 32) | (unsigned)(~i);
    }
  }
  for (int i = tid + K * BT; i < N; i += BT) {   // tail
    const float s = cp[(size_t)i * C];
    if (s > THRV) {
      const unsigned u = __float_as_uint(s);
      const int pos = atomicAdd(&hist[bktOf(u)], 1);
      sk[pos] = ((unsigned long long)u << 32) | (unsigned)(~i);
    }
  }
  __syncthreads();

  // ---- Phase 3: per-bucket insertion sort (descending u64) ----
  for (int bk = tid; bk < NB; bk += BT) {
    const int lo = (bk == NB - 1) ? 0 : hist[bk + 1];  // post-scatter = end of next bucket
    const int hi = hist[bk];
    for (int x = lo + 1; x < hi; ++x) {
      const unsigned long long v = sk[x];
      int y = x - 1;
      while (y >= lo && sk[y] < v) { sk[y + 1] = sk[y]; --y; }
      sk[y + 1] = v;
    }
  }
  __syncthreads();

  // ---- Phase 4: batched sorted scan ----
  int nk = 0;
  for (int base = 0; base < cn && nk < MAXDET; base += 64) {
    const int nc = min(64, cn - base);
    const bool valid = lane < nc;
    unsigned long long key = valid ? sk[base + lane] : 0ull;
    const float score = __uint_as_float((unsigned)(key >> 32));
    const int idx = (int)(~(unsigned)key);
    float4 bx = make_float4(0.f, 0.f, 0.f, 0.f);
    if (valid) bx = bb4[idx];
    const float area = (bx.z - bx.x) * (bx.w - bx.y);

    // vs already-kept: wave w checks kept entries w, w+8, ...
    bool kill = false;
    for (int e = wid; e < nk; e += BT / 64) {
      const float4 q = kboxS[e];
      kill = kill || killpair(q.x, q.y, q.z, q.w, kareaS[e],
                              bx.x, bx.y, bx.z, bx.w, area);
    }
    {
      const unsigned long long bm = __ballot(valid && kill);
      if (lane == 0) wkill[wid] = bm;
    }
    // in-batch 64x64 matrix: wave w computes columns j = 8w .. 8w+7
    {
      const int cb = wid * 8;
#pragma unroll
      for (int jj = 0; jj < 8; ++jj) {
        const int j = cb + jj;
        if (j < nc) {
          const float jx1 = __int_as_float(__builtin_amdgcn_readlane(__float_as_int(bx.x), j));
          const float jy1 = __int_as_float(__builtin_amdgcn_readlane(__float_as_int(bx.y), j));
          const float jx2 = __int_as_float(__builtin_amdgcn_readlane(__float_as_int(bx.z), j));
          const float jy2 = __int_as_float(__builtin_amdgcn_readlane(__float_as_int(bx.w), j));
          const float ja  = __int_as_float(__builtin_amdgcn_readlane(__float_as_int(area), j));
          const bool kij = valid && killpair(jx1, jy1, jx2, jy2, ja,
                                             bx.x, bx.y, bx.z, bx.w, area);
          const unsigned long long bm = __ballot(kij);
          if (lane == 0) killby[j] = bm;
        }
      }
    }
    __syncthreads();                      // wkill/killby ready

    // serial mask resolution (all threads redundantly; masks via readlane)
    unsigned long long kmask = 0;
#pragma unroll
    for (int w = 0; w < BT / 64; ++w) kmask |= wkill[w];
    unsigned long long alive = ~kmask;
    alive &= (nc >= 64) ? ~0ull : ((1ull << nc) - 1ull);
    const unsigned long long kb = killby[lane];
    for (int j = 0; j < 64; ++j) {
      if ((alive >> j) & 1ull) {
        const unsigned klo = (unsigned)__builtin_amdgcn_readlane((int)(unsigned)kb, j);
        const unsigned khi = (unsigned)__builtin_amdgcn_readlane((int)(unsigned)(kb >> 32), j);
        const unsigned long long km = ((unsigned long long)khi << 32) | klo;
        alive &= ~(km & ((~1ull) << j));  // kill only lower-score (higher j') bits
      }
    }
    // append kept (wave 0 writes; alive/nk uniform across all threads)
    if (wid == 0) {
      const int rank = (int)__popcll(alive & ((1ull << lane) - 1ull));
      if (((alive >> lane) & 1ull) && (nk + rank < MAXDET)) {
        kboxS[nk + rank] = bx;
        kscoreS[nk + rank] = score;
        kareaS[nk + rank] = area;
      }
    }
    nk += min((int)__popcll(alive), MAXDET - nk);
    __syncthreads();                      // kept visible for next batch
  }

  // ---- Phase 5: emit ----
  float* ko  = ksc + (size_t)bc * MAXDET;
  float* kbo = kbx + (size_t)bc * MAXDET * 4;
  for (int e = tid; e < MAXDET; e += BT) {
    if (e < nk) {
      const float4 q = kboxS[e];
      ko[e] = kscoreS[e];
      kbo[e * 4 + 0] = q.x; kbo[e * 4 + 1] = q.y;
      kbo[e * 4 + 2] = q.z; kbo[e * 4 + 3] = q.w;
    } else {
      ko[e] = NEGV;
      kbo[e * 4 + 0] = 0.f; kbo[e * 4 + 1] = 0.f;
      kbo[e * 4 + 2] = 0.f; kbo[e * 4 + 3] = 0.f;
    }
  }
}

// ---------------------------------------------------------------------------
// Kernel 2: per-image top-100 = 80-way merge of per-class descending lists.
// Single wave, DPP reduces, LDS-resident score slab, deferred box gather.
// ---------------------------------------------------------------------------
__global__ __launch_bounds__(64, 1) void topk_kernel(
    const float* __restrict__ ksc, const float* __restrict__ kbx,
    float* __restrict__ out, int B, int C)
{
  const int b = blockIdx.x;
  const int lane = threadIdx.x;
  const int T = C * MAXDET;
  const float* s0 = ksc + (size_t)b * T;
  float* ob = out;                              // [B][100][4]
  float* os = out + (size_t)B * MAXDET * 4;     // [B][100]
  float* ol = os + (size_t)B * MAXDET;          // [B][100] labels as float

  __shared__ float ssc[8192];
  __shared__ int   wfi[MAXDET];
  __shared__ float wsc[MAXDET];
  const bool uselds = (T <= 8192);
  if (uselds)
    for (int i = lane; i < T; i += 64) ssc[i] = s0[i];
  __syncthreads();

  int h0 = 0, h1 = 0;
  const int c0 = lane;
  const int c1 = lane + 64;

  for (int m = 0; m < MAXDET; ++m) {
    float bv = -FLT_MAX; int bf = 0x7FFFFFFF;
    if (c0 < C && h0 < MAXDET) {
      const int f = c0 * MAXDET + h0;
      amax2(bv, bf, uselds ? ssc[f] : s0[f], f);
    }
    if (c1 < C && h1 < MAXDET) {
      const int f = c1 * MAXDET + h1;
      amax2(bv, bf, uselds ? ssc[f] : s0[f], f);
    }
    const float gmax = wave_fmax_b(bv);
    if (gmax <= THRV) {
      for (int mm = m + lane; mm < MAXDET; mm += 64) wfi[mm] = -1;
      break;
    }
    const unsigned gf =
        wave_umin_b((bv == gmax) ? (unsigned)bf : 0xFFFFFFFFu);
    const int wc = (int)gf / MAXDET;
    if (lane == (wc & 63)) { if (wc == c0) ++h0; else ++h1; }
    if (lane == 0) { wfi[m] = (int)gf; wsc[m] = gmax; }
  }
  __syncthreads();

  for (int e = lane; e < MAXDET; e += 64) {
    const int f = wfi[e];
    float* od = ob + ((size_t)b * MAXDET + e) * 4;
    if (f < 0) {
      od[0] = -1.f; od[1] = -1.f; od[2] = -1.f; od[3] = -1.f;
      os[(size_t)b * MAXDET + e] = -1.f;
      ol[(size_t)b * MAXDET + e] = -1.f;
    } else {
      const float* bp = kbx + ((size_t)b * T + f) * 4;
      od[0] = bp[0]; od[1] = bp[1]; od[2] = bp[2]; od[3] = bp[3];
      os[(size_t)b * MAXDET + e] = wsc[e];
      ol[(size_t)b * MAXDET + e] = (float)(f / MAXDET);
    }
  }
}

extern "C" void kernel_launch(void* const* d_in, const int* in_sizes, int n_in,
                              void* d_out, int out_size, void* d_ws, size_t ws_size,
                              hipStream_t stream) {
  const float* boxes = (const float*)d_in[0];  // (B, N, 4) f32
  const float* cls   = (const float*)d_in[1];  // (B, N, C) f32
  const int B = out_size / (MAXDET * 6);       // 4 box + 1 score + 1 label
  const int N = in_sizes[0] / (B * 4);
  const int C = in_sizes[1] / (B * N);

  char* ws = (char*)d_ws;
  unsigned long long* skey = (unsigned long long*)ws;
  ws += (size_t)B * C * N * 8;                               // sorted keys
  float* kbx = (float*)ws; ws += (size_t)B * C * MAXDET * 16; // kept boxes
  float* ksc = (float*)ws; ws += (size_t)B * C * MAXDET * 4;  // kept scores

  nms_kernel<20, 512><<<dim3(B * C), dim3(512), 0, stream>>>(
      boxes, cls, skey, ksc, kbx, N, C);
  topk_kernel<<<dim3(B), dim3(64), 0, stream>>>(ksc, kbx, (float*)d_out, B, C);
}

// Round 6
// 154.358 us; speedup vs baseline: 2.7851x; 1.1863x over previous
//
#include <hip/hip_runtime.h>
#include <hip/hip_bf16.h>
#include <float.h>
#include <stdint.h>

// Forbid FMA contraction: reference (numpy fp32) rounds every mul/add
// separately; a fused (a1+a2)-iw*ih could flip an iou>0.5 decision.
#pragma clang fp contract(off)

#define NEGV   (-1e9f)
#define THRV   (0.05f)
#define MAXDET 100
#define NB     1152        // score buckets (3 per thread at BT=512 -> 384 thr)
#define BKBASE 31385       // (bits(0.05f) >> 15)
#define SLAB   7168        // LDS-resident sort slots (56 KB); overflow -> global
#define TKCAP  1024        // LDS-resident topk candidates; overflow -> global

__device__ __forceinline__ int bktOf(unsigned u) {
  int v = (int)(u >> 15) - BKBASE;          // monotone in float for s > 0
  return v < 0 ? 0 : (v > NB - 1 ? NB - 1 : v);
}

// Bit-exact "(iou > 0.5)" decision. Certain cases via the two-sided window
// (margin 1e-5 >> max rounding error); ambiguous window does the exact
// reference IEEE divide.
__device__ __forceinline__ bool killpair(
    float qx1, float qy1, float qx2, float qy2, float qa,
    float x1, float y1, float x2, float y2, float a)
{
  const float iw = fminf(qx2, x2) - fmaxf(qx1, x1);
  const float ih = fminf(qy2, y2) - fmaxf(qy1, y1);
  if (iw <= 0.f || ih <= 0.f) return false;
  const float inter = iw * ih;
  const float den = fmaxf((qa + a) - inter, 1e-8f);
  const float i2 = inter + inter;
  if (i2 > den * 1.00001f) return true;
  if (i2 < den * 0.99999f) return false;
  return (inter / den) > 0.5f;
}

// suffix-sum of hist[] (descending bucket layout): hist[bk] becomes the start
// position of bucket bk (bucket NB-1 first). Returns total count.
template<int BT>
__device__ __forceinline__ int suffix_scan(int* hist, int* wtot,
                                           int tid, int lane, int wid) {
  int c0 = 0, c1 = 0, c2 = 0;
  if (tid < NB / 3) {
    c0 = hist[NB - 1 - 3 * tid];
    c1 = hist[NB - 2 - 3 * tid];
    c2 = hist[NB - 3 - 3 * tid];
  }
  const int tsum = c0 + c1 + c2;
  int inc = tsum;
#pragma unroll
  for (int off = 1; off < 64; off <<= 1) {
    const int u = __shfl_up(inc, off, 64);
    if (lane >= off) inc += u;
  }
  if (lane == 63) wtot[wid] = inc;
  __syncthreads();
  int wbase = 0, tot = 0;
#pragma unroll
  for (int w = 0; w < BT / 64; ++w) {
    const int v = wtot[w];
    if (w < wid) wbase += v;
    tot += v;
  }
  const int excl = wbase + inc - tsum;
  if (tid < NB / 3) {
    hist[NB - 1 - 3 * tid] = excl;
    hist[NB - 2 - 3 * tid] = excl + c0;
    hist[NB - 3 - 3 * tid] = excl + c0 + c1;
  }
  __syncthreads();
  return tot;
}

// ---------------------------------------------------------------------------
// Kernel 0: cls (B,N,C) -> clsT (B,C,N), LDS-tiled, fully coalesced.
// ---------------------------------------------------------------------------
__global__ __launch_bounds__(256, 1) void transpose_kernel(
    const float* __restrict__ cls, float* __restrict__ clsT, int N, int C)
{
  __shared__ float tile[32][33];
  const int b = blockIdx.z;
  const int n0 = blockIdx.x * 32, c0 = blockIdx.y * 32;
  const int tx = threadIdx.x, ty = threadIdx.y;   // 32 x 8
#pragma unroll
  for (int r = ty; r < 32; r += 8) {
    const int n = n0 + r, c = c0 + tx;
    if (n < N && c < C) tile[r][tx] = cls[((size_t)b * N + n) * C + c];
  }
  __syncthreads();
#pragma unroll
  for (int r = ty; r < 32; r += 8) {
    const int c = c0 + r, n = n0 + tx;
    if (n < N && c < C) clsT[((size_t)b * C + c) * N + n] = tile[tx][r];
  }
}

// ---------------------------------------------------------------------------
// Kernel 1: per-(image,class) sorted-scan NMS, sort slab in LDS.
// ---------------------------------------------------------------------------
template<int BT>
__global__ __launch_bounds__(BT, 1) void nms_kernel(
    const float* __restrict__ boxes, const float* __restrict__ clsT,
    unsigned long long* __restrict__ skg_all,
    float* __restrict__ ksc, float* __restrict__ kbx, int N, int C)
{
#pragma clang fp contract(off)
  const int bc = blockIdx.x;
  const int tid = threadIdx.x, lane = tid & 63, wid = tid >> 6;

  const float* ct = clsT + (size_t)bc * N;       // contiguous class column
  const float4* bb4 = (const float4*)(boxes + (size_t)(bc / C) * N * 4);
  unsigned long long* skg = skg_all + (size_t)bc * N;  // overflow only

  __shared__ unsigned long long slab[SLAB];
  __shared__ int hist[NB];
  __shared__ int wtot[BT / 64];
  __shared__ float4 kboxS[MAXDET];
  __shared__ float  kscoreS[MAXDET];
  __shared__ float  kareaS[MAXDET];
  __shared__ unsigned long long wkill[BT / 64];
  __shared__ unsigned long long killby[64];

  // ---- Phase 0: histogram of alive scores (coalesced read) ----
  for (int i = tid; i < NB; i += BT) hist[i] = 0;
  __syncthreads();
  for (int i = tid; i < N; i += BT) {
    const float s = ct[i];
    if (s > THRV) atomicAdd(&hist[bktOf(__float_as_uint(s))], 1);
  }
  __syncthreads();

  // ---- Phase 1: starts (descending layout) ----
  const int cn = suffix_scan<BT>(hist, wtot, tid, lane, wid);

  // ---- Phase 2: scatter keys (score_bits<<32 | ~idx) into LDS slab ----
  for (int i = tid; i < N; i += BT) {
    const float s = ct[i];
    if (s > THRV) {
      const unsigned u = __float_as_uint(s);
      const int pos = atomicAdd(&hist[bktOf(u)], 1);
      const unsigned long long key =
          ((unsigned long long)u << 32) | (unsigned)(~i);
      if (pos < SLAB) slab[pos] = key; else skg[pos] = key;
    }
  }
  __syncthreads();

  // ---- Phase 3: per-bucket insertion sort (descending u64) in LDS ----
  for (int bk = tid; bk < NB; bk += BT) {
    const int lo = (bk == NB - 1) ? 0 : hist[bk + 1];  // post-scatter = end of next bucket
    const int hi = hist[bk];
    for (int x = lo + 1; x < hi; ++x) {
      const unsigned long long v = (x < SLAB) ? slab[x] : skg[x];
      int y = x - 1;
      while (y >= lo) {
        const unsigned long long w = (y < SLAB) ? slab[y] : skg[y];
        if (w >= v) break;
        if (y + 1 < SLAB) slab[y + 1] = w; else skg[y + 1] = w;
        --y;
      }
      if (y + 1 < SLAB) slab[y + 1] = v; else skg[y + 1] = v;
    }
  }
  __syncthreads();

  // ---- Phase 4: batched sorted scan (64/batch) ----
  int nk = 0;
  for (int base = 0; base < cn && nk < MAXDET; base += 64) {
    const int nc = min(64, cn - base);
    const bool valid = lane < nc;
    const int p = base + lane;
    unsigned long long key = 0ull;
    if (valid) key = (p < SLAB) ? slab[p] : skg[p];
    const float score = __uint_as_float((unsigned)(key >> 32));
    const int idx = (int)(~(unsigned)key);
    float4 bx = make_float4(0.f, 0.f, 0.f, 0.f);
    if (valid) bx = bb4[idx];
    const float area = (bx.z - bx.x) * (bx.w - bx.y);

    // vs already-kept: wave w checks kept entries w, w+8, ...
    bool kill = false;
    for (int e = wid; e < nk; e += BT / 64) {
      const float4 q = kboxS[e];
      kill = kill || killpair(q.x, q.y, q.z, q.w, kareaS[e],
                              bx.x, bx.y, bx.z, bx.w, area);
    }
    {
      const unsigned long long bm = __ballot(valid && kill);
      if (lane == 0) wkill[wid] = bm;
    }
    // in-batch 64x64 matrix: wave w computes columns j = 8w .. 8w+7
    {
      const int cb = wid * 8;
#pragma unroll
      for (int jj = 0; jj < 8; ++jj) {
        const int j = cb + jj;
        if (j < nc) {
          const float jx1 = __int_as_float(__builtin_amdgcn_readlane(__float_as_int(bx.x), j));
          const float jy1 = __int_as_float(__builtin_amdgcn_readlane(__float_as_int(bx.y), j));
          const float jx2 = __int_as_float(__builtin_amdgcn_readlane(__float_as_int(bx.z), j));
          const float jy2 = __int_as_float(__builtin_amdgcn_readlane(__float_as_int(bx.w), j));
          const float ja  = __int_as_float(__builtin_amdgcn_readlane(__float_as_int(area), j));
          const bool kij = valid && killpair(jx1, jy1, jx2, jy2, ja,
                                             bx.x, bx.y, bx.z, bx.w, area);
          const unsigned long long bm = __ballot(kij);
          if (lane == 0) killby[j] = bm;
        }
      }
    }
    __syncthreads();                      // wkill/killby ready

    // serial mask resolution (all threads redundantly; masks via readlane)
    unsigned long long kmask = 0;
#pragma unroll
    for (int w = 0; w < BT / 64; ++w) kmask |= wkill[w];
    unsigned long long alive = ~kmask;
    alive &= (nc >= 64) ? ~0ull : ((1ull << nc) - 1ull);
    const unsigned long long kb = killby[lane];
    for (int j = 0; j < 64; ++j) {
      if ((alive >> j) & 1ull) {
        const unsigned klo = (unsigned)__builtin_amdgcn_readlane((int)(unsigned)kb, j);
        const unsigned khi = (unsigned)__builtin_amdgcn_readlane((int)(unsigned)(kb >> 32), j);
        const unsigned long long km = ((unsigned long long)khi << 32) | klo;
        alive &= ~(km & ((~1ull) << j));  // kill only lower-score (higher j') bits
      }
    }
    // append kept (wave 0 writes; alive/nk uniform across all threads)
    if (wid == 0) {
      const int rank = (int)__popcll(alive & ((1ull << lane) - 1ull));
      if (((alive >> lane) & 1ull) && (nk + rank < MAXDET)) {
        kboxS[nk + rank] = bx;
        kscoreS[nk + rank] = score;
        kareaS[nk + rank] = area;
      }
    }
    nk += min((int)__popcll(alive), MAXDET - nk);
    __syncthreads();                      // kept visible for next batch
  }

  // ---- Phase 5: emit ----
  float* ko  = ksc + (size_t)bc * MAXDET;
  float* kbo = kbx + (size_t)bc * MAXDET * 4;
  for (int e = tid; e < MAXDET; e += BT) {
    if (e < nk) {
      const float4 q = kboxS[e];
      ko[e] = kscoreS[e];
      kbo[e * 4 + 0] = q.x; kbo[e * 4 + 1] = q.y;
      kbo[e * 4 + 2] = q.z; kbo[e * 4 + 3] = q.w;
    } else {
      ko[e] = NEGV;
      kbo[e * 4 + 0] = 0.f; kbo[e * 4 + 1] = 0.f;
      kbo[e * 4 + 2] = 0.f; kbo[e * 4 + 3] = 0.f;
    }
  }
}

// ---------------------------------------------------------------------------
// Kernel 2: per-image top-100 via radix-select over the 1152 score buckets:
// histogram -> threshold bucket -> compact ~107 candidates -> rank-by-count.
// Key (score_bits<<32 | ~flat_idx) == lax.top_k (value desc, idx asc).
// ---------------------------------------------------------------------------
template<int BT>
__global__ __launch_bounds__(BT, 1) void topk_kernel(
    const float* __restrict__ ksc, const float* __restrict__ kbx,
    unsigned long long* __restrict__ gcand_all,
    float* __restrict__ out, int B, int C)
{
  const int b = blockIdx.x;
  const int tid = threadIdx.x, lane = tid & 63, wid = tid >> 6;
  const int T = C * MAXDET;
  const float* s0 = ksc + (size_t)b * T;
  unsigned long long* gc = gcand_all + (size_t)b * T;   // overflow only
  float* ob = out;                              // [B][100][4]
  float* os = out + (size_t)B * MAXDET * 4;     // [B][100]
  float* ol = os + (size_t)B * MAXDET;          // [B][100] labels as float

  __shared__ int hist[NB];
  __shared__ int wtot[BT / 64];
  __shared__ unsigned long long cand[TKCAP];
  __shared__ int tB, cposS;

  for (int i = tid; i < NB; i += BT) hist[i] = 0;
  if (tid == 0) { cposS = 0; tB = 0; }
  __syncthreads();
  for (int f = tid; f < T; f += BT) {
    const float s = s0[f];
    if (s > THRV) atomicAdd(&hist[bktOf(__float_as_uint(s))], 1);
  }
  __syncthreads();
  suffix_scan<BT>(hist, wtot, tid, lane, wid);
  // threshold bucket: smallest bk with start[bk] < MAXDET
  for (int bk = tid; bk < NB; bk += BT)
    if (hist[bk] < MAXDET && (bk == 0 || hist[bk - 1] >= MAXDET)) tB = bk;
  __syncthreads();
  const int t = tB;
  for (int f = tid; f < T; f += BT) {
    const float s = s0[f];
    if (s > THRV) {
      const unsigned u = __float_as_uint(s);
      if (bktOf(u) >= t) {
        const int p = atomicAdd(&cposS, 1);
        const unsigned long long key =
            ((unsigned long long)u << 32) | (unsigned)(~f);
        if (p < TKCAP) cand[p] = key; else gc[p] = key;
      }
    }
  }
  __syncthreads();
  const int nc = cposS;
  const int nw = min(nc, MAXDET);
  // prefill only the never-written slots (no race with winner writes)
  for (int s2 = nw + tid; s2 < MAXDET; s2 += BT) {
    float* od = ob + ((size_t)b * MAXDET + s2) * 4;
    od[0] = -1.f; od[1] = -1.f; od[2] = -1.f; od[3] = -1.f;
    os[(size_t)b * MAXDET + s2] = -1.f;
    ol[(size_t)b * MAXDET + s2] = -1.f;
  }
  // rank by counting (keys unique -> ranks unique), emit winners
  for (int e = tid; e < nc; e += BT) {
    const unsigned long long k = (e < TKCAP) ? cand[e] : gc[e];
    int rank = 0;
    for (int j = 0; j < nc; ++j) {
      const unsigned long long o = (j < TKCAP) ? cand[j] : gc[j];
      rank += (o > k) ? 1 : 0;
    }
    if (rank < MAXDET) {
      const int f = (int)(~(unsigned)k);
      const float sc = __uint_as_float((unsigned)(k >> 32));
      const float* bp = kbx + ((size_t)b * T + f) * 4;
      float* od = ob + ((size_t)b * MAXDET + rank) * 4;
      od[0] = bp[0]; od[1] = bp[1]; od[2] = bp[2]; od[3] = bp[3];
      os[(size_t)b * MAXDET + rank] = sc;
      ol[(size_t)b * MAXDET + rank] = (float)(f / MAXDET);
    }
  }
}

extern "C" void kernel_launch(void* const* d_in, const int* in_sizes, int n_in,
                              void* d_out, int out_size, void* d_ws, size_t ws_size,
                              hipStream_t stream) {
  const float* boxes = (const float*)d_in[0];  // (B, N, 4) f32
  const float* cls   = (const float*)d_in[1];  // (B, N, C) f32
  const int B = out_size / (MAXDET * 6);       // 4 box + 1 score + 1 label
  const int N = in_sizes[0] / (B * 4);
  const int C = in_sizes[1] / (B * N);

  char* ws = (char*)d_ws;
  float* clsT = (float*)ws; ws += (size_t)B * C * N * 4;       // transposed cls
  float* kbx = (float*)ws;  ws += (size_t)B * C * MAXDET * 16; // kept boxes
  float* ksc = (float*)ws;  ws += (size_t)B * C * MAXDET * 4;  // kept scores
  unsigned long long* gcand = (unsigned long long*)ws;
  ws += (size_t)B * C * MAXDET * 8;                            // topk overflow
  unsigned long long* skg = (unsigned long long*)ws;           // sort overflow
  // (skg region only ever touched if a class has >SLAB alive candidates)

  transpose_kernel<<<dim3((N + 31) / 32, (C + 31) / 32, B), dim3(32, 8),
                     0, stream>>>(cls, clsT, N, C);
  nms_kernel<512><<<dim3(B * C), dim3(512), 0, stream>>>(
      boxes, clsT, skg, ksc, kbx, N, C);
  topk_kernel<512><<<dim3(B), dim3(512), 0, stream>>>(
      ksc, kbx, gcand, (float*)d_out, B, C);
}